// Round 6
// baseline (33.140 us; speedup 1.0000x reference)
//
#include <hip/hip_runtime.h>

#define BS    2
#define NTOK  2048
#define NH    4
#define W     64
#define HALF  32
#define DTILE 16            // destination tokens per block
#define ND    2             // destination tokens per wave
#define NROW  17            // window-row iterations per lane r-group
#define ROWS  80            // staged rows per tensor: DTILE + 64
#define NWAVE 8             // waves per block

// DPP butterfly-add within a 16-lane row. {xor1, xor2, xor7, xor8} spans the
// 4-bit lane subspace -> sums all 16 lanes of the row into every lane.
template<int CTRL>
__device__ __forceinline__ float fadd_dpp(float x) {
    int y = __builtin_amdgcn_mov_dpp(__float_as_int(x), CTRL, 0xF, 0xF, true);
    return x + __int_as_float(y);
}

// Block: 512 threads = 8 waves, one (b,h), 16 consecutive d's.
// Stage k rows [d0-32, d0+47] into smem[0..79], v rows into smem[80..159]
// (80 x 256B each, async direct-to-LDS), then each wave computes 2 d's with
// the fused no-max-softmax pipeline (scores <= 0 -> exp2 never overflows;
// normalize by 1/sum at the store).
__global__ __launch_bounds__(512, 8) void l1attn_win64_v6(
    const float* __restrict__ v,
    const float* __restrict__ q,
    const float* __restrict__ k,
    float* __restrict__ out)
{
    __shared__ alignas(16) float smem[2 * ROWS * W];   // 40 KB

    const int tid  = threadIdx.x;
    const int lane = tid & 63;
    const int widx = tid >> 6;

    // 1024 blocks, 8 XCDs -> bijective swizzle, 128-block contiguous chunks
    int bid = blockIdx.x;
    bid = (bid & 7) * 128 + (bid >> 3);

    const int bh = bid >> 7;                 // 128 blocks per (b,h)
    const int d0 = (bid & 127) * DTILE;
    const int h  = bh & (NH - 1);
    const int b  = bh >> 2;
    const int base = b * (NTOK * NH * W) + h * W;

    // ---- async stage: 2*80 rows x 256B, 5 instrs/wave, coalesced ----------
    // chunk c = i*512 + tid covers LDS bytes [c*16, c*16+16); row = c>>4.
    #pragma unroll
    for (int i = 0; i < 5; ++i) {
        const int c    = i * 512 + tid;
        const int row  = c >> 4;                         // 0..159
        const int sub  = c & 15;
        const int isV  = (row >= ROWS);                  // wave-uniform
        const int trow = isV ? row - ROWS : row;
        const int src  = (d0 - HALF + trow) & (NTOK - 1);
        const float* g = (isV ? v : k) + base + src * (NH * W) + sub * 4;
        char* l = (char*)smem + (i * 512 + widx * 64) * 16;
        __builtin_amdgcn_global_load_lds(
            (const __attribute__((address_space(1))) void*)g,
            (__attribute__((address_space(3))) void*)l, 16, 0, 0);
    }

    // ---- q rows for this wave's 2 destinations (overlaps the stage) -------
    const int l16 = lane & 15;
    const int r   = lane >> 4;
    const int c0  = l16 * 4;
    const int dw0 = d0 + widx * ND;

    float4 qv[ND];
    #pragma unroll
    for (int dd = 0; dd < ND; ++dd)
        qv[dd] = *(const float4*)(q + base + (dw0 + dd) * (NH * W) + c0);

    __syncthreads();   // drains vmcnt: staged data + q visible

    float4 acc[ND];
    float  ssum[ND];
    #pragma unroll
    for (int dd = 0; dd < ND; ++dd) {
        acc[dd] = make_float4(0.f, 0.f, 0.f, 0.f);
        ssum[dd] = 0.f;
    }

    // exp(s * -1/8) = exp2(s * SC); scores in [-~70, 0] -> no max needed
    const float SC = -0.125f * 1.44269504088896f;
    const int lr0 = widx * ND + r;           // staged row at it=0

    #pragma unroll
    for (int it = 0; it < NROW; ++it) {
        int lrow = lr0 + it * 4;
        lrow = lrow > (ROWS - 1) ? (ROWS - 1) : lrow;   // masked lanes: clamp
        const float4 kv = *(const float4*)&smem[lrow * W + c0];
        const float4 vv = *(const float4*)&smem[(ROWS + lrow) * W + c0];
        #pragma unroll
        for (int dd = 0; dd < ND; ++dd) {
            float t = fabsf(qv[dd].x - kv.x) + fabsf(qv[dd].y - kv.y)
                    + fabsf(qv[dd].z - kv.z) + fabsf(qv[dd].w - kv.w);
            t = fadd_dpp<0xB1>(t);           // 16-lane channel reduce (VALU)
            t = fadd_dpp<0x4E>(t);
            t = fadd_dpp<0x141>(t);
            t = fadd_dpp<0x128>(t);
            float sc = t * SC;
            // j = m - dd invalid exactly at (it==0 && r<dd) or (it==16 && r>=dd)
            if (it == 0)        sc = (r <  dd) ? -1e30f : sc;
            if (it == NROW - 1) sc = (r >= dd) ? -1e30f : sc;
            const float p = __builtin_amdgcn_exp2f(sc);   // invalid -> 0
            ssum[dd] += p;
            acc[dd].x = fmaf(p, vv.x, acc[dd].x);
            acc[dd].y = fmaf(p, vv.y, acc[dd].y);
            acc[dd].z = fmaf(p, vv.z, acc[dd].z);
            acc[dd].w = fmaf(p, vv.w, acc[dd].w);
        }
    }

    // reduce across the 4 r-groups, normalize, store
    #pragma unroll
    for (int dd = 0; dd < ND; ++dd) {
        ssum[dd] += __shfl_xor(ssum[dd], 16);
        ssum[dd] += __shfl_xor(ssum[dd], 32);
        acc[dd].x += __shfl_xor(acc[dd].x, 16);
        acc[dd].y += __shfl_xor(acc[dd].y, 16);
        acc[dd].z += __shfl_xor(acc[dd].z, 16);
        acc[dd].w += __shfl_xor(acc[dd].w, 16);
        acc[dd].x += __shfl_xor(acc[dd].x, 32);
        acc[dd].y += __shfl_xor(acc[dd].y, 32);
        acc[dd].z += __shfl_xor(acc[dd].z, 32);
        acc[dd].w += __shfl_xor(acc[dd].w, 32);
    }
    if (r == 0) {
        #pragma unroll
        for (int dd = 0; dd < ND; ++dd) {
            const float inv = 1.0f / ssum[dd];
            *(float4*)(out + base + (dw0 + dd) * (NH * W) + c0) =
                make_float4(acc[dd].x * inv, acc[dd].y * inv,
                            acc[dd].z * inv, acc[dd].w * inv);
        }
    }
}

extern "C" void kernel_launch(void* const* d_in, const int* in_sizes, int n_in,
                              void* d_out, int out_size, void* d_ws, size_t ws_size,
                              hipStream_t stream) {
    // setup_inputs order: v, q, k, coo, dst_mxlen, src_mxlen
    const float* v = (const float*)d_in[0];
    const float* q = (const float*)d_in[1];
    const float* k = (const float*)d_in[2];
    float* out = (float*)d_out;

    const int blocks = (BS * NH * NTOK) / DTILE;   // 1024
    hipLaunchKernelGGL(l1attn_win64_v6, dim3(blocks), dim3(512), 0, stream,
                       v, q, k, out);
}

// Round 7
// 22.263 us; speedup vs baseline: 1.4885x; 1.4885x over previous
//
#include <hip/hip_runtime.h>

#define BS    2
#define NTOK  2048
#define NH    4
#define W     64
#define HALF  32
#define DTILE 16            // destination tokens per block
#define ND    4             // destination tokens per wave
#define NROW  17            // window-row iterations per lane r-group
#define ROWS  80            // staged k rows per block: DTILE + 64

// DPP butterfly-add within a 16-lane row. {xor1, xor2, xor7, xor8} spans the
// 4-bit lane subspace -> sums all 16 lanes of the row into every lane.
template<int CTRL>
__device__ __forceinline__ float fadd_dpp(float x) {
    int y = __builtin_amdgcn_mov_dpp(__float_as_int(x), CTRL, 0xF, 0xF, true);
    return x + __int_as_float(y);
}

// Block: 256 threads = 4 waves, one (b,h), 16 consecutive d's.
// k rows [d0-32, d0+47] staged in LDS (20 KB, async direct-to-LDS).
// v rows read straight from global (L2-resident, coalesced 1KB/instr).
// Fused no-max softmax: scores <= 0 so exp2 never overflows; normalize by
// 1/sum at the store.
__global__ __launch_bounds__(256, 4) void l1attn_win64_v7(
    const float* __restrict__ v,
    const float* __restrict__ q,
    const float* __restrict__ k,
    float* __restrict__ out)
{
    __shared__ alignas(16) float ks[ROWS * W];     // 20 KB

    const int tid  = threadIdx.x;
    const int lane = tid & 63;
    const int widx = tid >> 6;

    // 1024 blocks, 8 XCDs -> bijective swizzle, 128-block contiguous chunks
    int bid = blockIdx.x;
    bid = (bid & 7) * 128 + (bid >> 3);

    const int bh = bid >> 7;                 // 128 blocks per (b,h)
    const int d0 = (bid & 127) * DTILE;
    const int h  = bh & (NH - 1);
    const int b  = bh >> 2;
    const int base = b * (NTOK * NH * W) + h * W;

    // ---- async stage of k: 80 rows x 256B = 1280 chunks of 16B ------------
    // chunk c = i*256 + tid ; row = c>>4, sub = c&15
    #pragma unroll
    for (int i = 0; i < 5; ++i) {
        const int c   = i * 256 + tid;
        const int row = c >> 4;
        const int sub = c & 15;
        const int src = (d0 - HALF + row) & (NTOK - 1);
        const float* g = k + base + src * (NH * W) + sub * 4;
        char* l = (char*)ks + (i * 256 + widx * 64) * 16;
        __builtin_amdgcn_global_load_lds(
            (const __attribute__((address_space(1))) void*)g,
            (__attribute__((address_space(3))) void*)l, 16, 0, 0);
    }

    // ---- q rows for this wave's 4 destinations (overlaps the stage) -------
    const int l16 = lane & 15;
    const int r   = lane >> 4;
    const int c0  = l16 * 4;
    const int dw0 = d0 + widx * ND;

    float4 qv[ND];
    #pragma unroll
    for (int dd = 0; dd < ND; ++dd)
        qv[dd] = *(const float4*)(q + base + (dw0 + dd) * (NH * W) + c0);

    __syncthreads();   // drains vmcnt: staged k visible

    float4 acc[ND];
    float  ssum[ND];
    #pragma unroll
    for (int dd = 0; dd < ND; ++dd) {
        acc[dd] = make_float4(0.f, 0.f, 0.f, 0.f);
        ssum[dd] = 0.f;
    }

    // exp(s * -1/8) = exp2(s * SC); scores in [-~70, 0] -> no max needed
    const float SC = -0.125f * 1.44269504088896f;
    const int lr0 = widx * ND + r;           // staged k row at it=0

    #pragma unroll
    for (int it = 0; it < NROW; ++it) {
        const int lrow = lr0 + it * 4;                    // < 80 always
        const int m    = lrow;                            // window row index
        const int src  = (d0 - HALF + m) & (NTOK - 1);
        const float4 kv = *(const float4*)&ks[lrow * W + c0];
        const float4 vv = *(const float4*)(v + base + src * (NH * W) + c0);
        #pragma unroll
        for (int dd = 0; dd < ND; ++dd) {
            float t = fabsf(qv[dd].x - kv.x) + fabsf(qv[dd].y - kv.y)
                    + fabsf(qv[dd].z - kv.z) + fabsf(qv[dd].w - kv.w);
            t = fadd_dpp<0xB1>(t);           // 16-lane channel reduce (VALU)
            t = fadd_dpp<0x4E>(t);
            t = fadd_dpp<0x141>(t);
            t = fadd_dpp<0x128>(t);
            float sc = t * SC;
            // j = m - dd invalid exactly at (it==0 && r<dd) or (it==16 && r>=dd)
            if (it == 0)        sc = (r <  dd) ? -1e30f : sc;
            if (it == NROW - 1) sc = (r >= dd) ? -1e30f : sc;
            const float p = __builtin_amdgcn_exp2f(sc);   // invalid -> 0
            ssum[dd] += p;
            acc[dd].x = fmaf(p, vv.x, acc[dd].x);
            acc[dd].y = fmaf(p, vv.y, acc[dd].y);
            acc[dd].z = fmaf(p, vv.z, acc[dd].z);
            acc[dd].w = fmaf(p, vv.w, acc[dd].w);
        }
    }

    // reduce across the 4 r-groups, normalize, store
    #pragma unroll
    for (int dd = 0; dd < ND; ++dd) {
        ssum[dd] += __shfl_xor(ssum[dd], 16);
        ssum[dd] += __shfl_xor(ssum[dd], 32);
        acc[dd].x += __shfl_xor(acc[dd].x, 16);
        acc[dd].y += __shfl_xor(acc[dd].y, 16);
        acc[dd].z += __shfl_xor(acc[dd].z, 16);
        acc[dd].w += __shfl_xor(acc[dd].w, 16);
        acc[dd].x += __shfl_xor(acc[dd].x, 32);
        acc[dd].y += __shfl_xor(acc[dd].y, 32);
        acc[dd].z += __shfl_xor(acc[dd].z, 32);
        acc[dd].w += __shfl_xor(acc[dd].w, 32);
    }
    if (r == 0) {
        #pragma unroll
        for (int dd = 0; dd < ND; ++dd) {
            const float inv = 1.0f / ssum[dd];
            *(float4*)(out + base + (dw0 + dd) * (NH * W) + c0) =
                make_float4(acc[dd].x * inv, acc[dd].y * inv,
                            acc[dd].z * inv, acc[dd].w * inv);
        }
    }
}

extern "C" void kernel_launch(void* const* d_in, const int* in_sizes, int n_in,
                              void* d_out, int out_size, void* d_ws, size_t ws_size,
                              hipStream_t stream) {
    // setup_inputs order: v, q, k, coo, dst_mxlen, src_mxlen
    const float* v = (const float*)d_in[0];
    const float* q = (const float*)d_in[1];
    const float* k = (const float*)d_in[2];
    float* out = (float*)d_out;

    const int blocks = (BS * NH * NTOK) / DTILE;   // 1024
    hipLaunchKernelGGL(l1attn_win64_v7, dim3(blocks), dim3(256), 0, stream,
                       v, q, k, out);
}

// Round 8
// 17.824 us; speedup vs baseline: 1.8592x; 1.2490x over previous
//
#include <hip/hip_runtime.h>

#define BS    2
#define NTOK  2048
#define NH    4
#define W     64
#define HALF  32
#define DTILE 16            // destination tokens per block
#define ND    4             // destination tokens per wave
#define NIT   9             // row iterations: 9*8 = 72 rows >= 67 union
#define ROWS  80            // staged rows per tensor: DTILE + 64

typedef float f32x2 __attribute__((ext_vector_type(2)));

// DPP butterfly-add within an 8-lane group: xor1 (0xB1), xor2 (0x4E), then
// half-mirror (0x141) which equals xor4 once bits 0-1 are already reduced.
// Sums all 8 lanes of the group into every lane.
template<int CTRL>
__device__ __forceinline__ float fadd_dpp(float x) {
    int y = __builtin_amdgcn_mov_dpp(__float_as_int(x), CTRL, 0xF, 0xF, true);
    return x + __int_as_float(y);
}

// Block: 256 threads = 4 waves, one (b,h), 16 consecutive d's.
// k rows [d0-32, d0+47] in ks[], v rows in vs[] (80 x 256B each, async
// direct-to-LDS). Lane = r*8 + l8: r = row-group (8 rows apart), l8 owns
// channels {4*l8..+3} and {32+4*l8..+3} (split so each ds_read_b128 request
// covers a dense, bank-uniform 1KB region). Fused no-max softmax.
__global__ __launch_bounds__(256, 4) void l1attn_win64_v8(
    const float* __restrict__ v,
    const float* __restrict__ q,
    const float* __restrict__ k,
    float* __restrict__ out)
{
    __shared__ alignas(16) float ks[ROWS * W];     // 20 KB
    __shared__ alignas(16) float vs[ROWS * W];     // 20 KB

    const int tid  = threadIdx.x;
    const int lane = tid & 63;
    const int widx = tid >> 6;

    // 1024 blocks, 8 XCDs -> bijective swizzle, 128-block contiguous chunks
    int bid = blockIdx.x;
    bid = (bid & 7) * 128 + (bid >> 3);

    const int bh = bid >> 7;                 // 128 blocks per (b,h)
    const int d0 = (bid & 127) * DTILE;
    const int h  = bh & (NH - 1);
    const int b  = bh >> 2;
    const int base = b * (NTOK * NH * W) + h * W;

    // ---- async stage of k and v: 80 rows x 256B each -----------------------
    // chunk c = i*256 + tid ; row = c>>4, sub = c&15 ; LDS layout linear.
    #pragma unroll
    for (int i = 0; i < 5; ++i) {
        const int c   = i * 256 + tid;
        const int row = c >> 4;
        const int sub = c & 15;
        const int src = (d0 - HALF + row) & (NTOK - 1);
        const float* gk = k + base + src * (NH * W) + sub * 4;
        const float* gv = v + base + src * (NH * W) + sub * 4;
        char* lk = (char*)ks + (i * 256 + widx * 64) * 16;
        char* lv = (char*)vs + (i * 256 + widx * 64) * 16;
        __builtin_amdgcn_global_load_lds(
            (const __attribute__((address_space(1))) void*)gk,
            (__attribute__((address_space(3))) void*)lk, 16, 0, 0);
        __builtin_amdgcn_global_load_lds(
            (const __attribute__((address_space(1))) void*)gv,
            (__attribute__((address_space(3))) void*)lv, 16, 0, 0);
    }

    // ---- q for this wave's 4 destinations (overlaps the stage) -------------
    const int l8 = lane & 7;
    const int r  = lane >> 3;                // 0..7
    const int cA = l8 * 4;                   // channels 4*l8 ..
    const int cB = 32 + l8 * 4;              // channels 32+4*l8 ..
    const int dw0 = d0 + widx * ND;

    float4 qA[ND], qB[ND];
    #pragma unroll
    for (int dd = 0; dd < ND; ++dd) {
        qA[dd] = *(const float4*)(q + base + (dw0 + dd) * (NH * W) + cA);
        qB[dd] = *(const float4*)(q + base + (dw0 + dd) * (NH * W) + cB);
    }

    __syncthreads();   // drains vmcnt: staged k/v visible

    float acc[ND][8];
    float ssum[ND];
    #pragma unroll
    for (int dd = 0; dd < ND; ++dd) {
        ssum[dd] = 0.f;
        #pragma unroll
        for (int c = 0; c < 8; ++c) acc[dd][c] = 0.f;
    }

    // exp(s * -1/8) = exp2(s * SC); scores <= 0 -> no max subtraction needed
    const float SC = -0.125f * 1.44269504088896f;
    const int mr0 = widx * ND + r;           // staged row at it=0

    #pragma unroll
    for (int it = 0; it < NIT; ++it) {
        int mrow = mr0 + it * 8;
        mrow = mrow > (ROWS - 1) ? (ROWS - 1) : mrow;  // masked lanes: clamp
        const float4 kA = *(const float4*)&ks[mrow * W + cA];
        const float4 kB = *(const float4*)&ks[mrow * W + cB];
        const float4 vA = *(const float4*)&vs[mrow * W + cA];
        const float4 vB = *(const float4*)&vs[mrow * W + cB];
        #pragma unroll
        for (int dd = 0; dd < ND; ++dd) {
            float t = ((fabsf(qA[dd].x - kA.x) + fabsf(qA[dd].y - kA.y))
                    +  (fabsf(qA[dd].z - kA.z) + fabsf(qA[dd].w - kA.w)))
                    + ((fabsf(qB[dd].x - kB.x) + fabsf(qB[dd].y - kB.y))
                    +  (fabsf(qB[dd].z - kB.z) + fabsf(qB[dd].w - kB.w)));
            t = fadd_dpp<0xB1>(t);           // 8-lane channel reduce (VALU)
            t = fadd_dpp<0x4E>(t);
            t = fadd_dpp<0x141>(t);
            float sc = t * SC;
            // j = it*8 + r - dd invalid at (it==0 && r<dd) or (it==8 && r>=dd)
            if (it == 0)       sc = (r <  dd) ? -1e30f : sc;
            if (it == NIT - 1) sc = (r >= dd) ? -1e30f : sc;
            const float p = __builtin_amdgcn_exp2f(sc);   // invalid -> 0
            ssum[dd] += p;
            f32x2 pp; pp.x = p; pp.y = p;
            f32x2* a2 = (f32x2*)acc[dd];
            a2[0] += pp * (*(const f32x2*)&vA.x);   // v_pk_fma_f32
            a2[1] += pp * (*(const f32x2*)&vA.z);
            a2[2] += pp * (*(const f32x2*)&vB.x);
            a2[3] += pp * (*(const f32x2*)&vB.z);
        }
    }

    // ---- reduce the 8 r-groups: xor8 via DPP row_ror:8, then shfl 16/32 ---
    #pragma unroll
    for (int dd = 0; dd < ND; ++dd) {
        ssum[dd] = fadd_dpp<0x128>(ssum[dd]);
        ssum[dd] += __shfl_xor(ssum[dd], 16);
        ssum[dd] += __shfl_xor(ssum[dd], 32);
        #pragma unroll
        for (int c = 0; c < 8; ++c) {
            acc[dd][c] = fadd_dpp<0x128>(acc[dd][c]);
            acc[dd][c] += __shfl_xor(acc[dd][c], 16);
            acc[dd][c] += __shfl_xor(acc[dd][c], 32);
        }
    }

    if (r == 0) {
        #pragma unroll
        for (int dd = 0; dd < ND; ++dd) {
            const float inv = __builtin_amdgcn_rcpf(ssum[dd]);
            *(float4*)(out + base + (dw0 + dd) * (NH * W) + cA) =
                make_float4(acc[dd][0] * inv, acc[dd][1] * inv,
                            acc[dd][2] * inv, acc[dd][3] * inv);
            *(float4*)(out + base + (dw0 + dd) * (NH * W) + cB) =
                make_float4(acc[dd][4] * inv, acc[dd][5] * inv,
                            acc[dd][6] * inv, acc[dd][7] * inv);
        }
    }
}

extern "C" void kernel_launch(void* const* d_in, const int* in_sizes, int n_in,
                              void* d_out, int out_size, void* d_ws, size_t ws_size,
                              hipStream_t stream) {
    // setup_inputs order: v, q, k, coo, dst_mxlen, src_mxlen
    const float* v = (const float*)d_in[0];
    const float* q = (const float*)d_in[1];
    const float* k = (const float*)d_in[2];
    float* out = (float*)d_out;

    const int blocks = (BS * NH * NTOK) / DTILE;   // 1024
    hipLaunchKernelGGL(l1attn_win64_v8, dim3(blocks), dim3(256), 0, stream,
                       v, q, k, out);
}